// Round 10
// baseline (257.075 us; speedup 1.0000x reference)
//
#include <hip/hip_runtime.h>

#define N_NODES 50000
#define N_EDGES 800000
#define IN_DIM 128
#define OUT_DIM 64
#define ROWS 64            // rows per block in gemm
#define NB 782             // buckets of 64 nodes
#define NB4 (NB * 4)       // (bucket, row&3) segments = 3128
#define CHUNK 4096         // edges per count/bin block
#define NCH ((N_EDGES + CHUNK - 1) / CHUNK)        // 196
#define SCAN_N (NB4 * NCH)                         // 613,088
#define SCAN_BLK 1024
#define NSC ((SCAN_N + SCAN_BLK - 1) / SCAN_BLK)   // 599

__device__ __forceinline__ unsigned short f2bf(float f) {
    unsigned u = __builtin_bit_cast(unsigned, f);
    u += 0x7FFF + ((u >> 16) & 1);          // round-to-nearest-even
    return (unsigned short)(u >> 16);
}
__device__ __forceinline__ float bf2f(unsigned short u) {
    unsigned x = ((unsigned)u) << 16;
    return __builtin_bit_cast(float, x);
}

// ---------------------------------------------------------------------------
// Kernel 1: h = x @ w, stored as bf16.  (f32 compute, bf16 store)
// ---------------------------------------------------------------------------
__global__ __launch_bounds__(256, 2) void gc_gemm(const float* __restrict__ x,
                                                  const float* __restrict__ w,
                                                  unsigned short* __restrict__ h16) {
    __shared__ float w_lds[IN_DIM * OUT_DIM];   // 32 KB
    __shared__ float x_lds[ROWS * IN_DIM];      // 32 KB (swizzled)

    const int tid = threadIdx.x;
    const int row0 = blockIdx.x * ROWS;

    const float4* w4 = reinterpret_cast<const float4*>(w);
    float4* wl4 = reinterpret_cast<float4*>(w_lds);
#pragma unroll
    for (int i = 0; i < 8; ++i) wl4[tid + i * 256] = w4[tid + i * 256];

    const float4* x4 = reinterpret_cast<const float4*>(x);
    float4* xl4 = reinterpret_cast<float4*>(x_lds);
#pragma unroll
    for (int i = 0; i < 8; ++i) {
        const int idx = tid + i * 256;
        const int r = idx >> 5;
        const int kc = idx & 31;
        const int g = row0 + r;
        float4 v = make_float4(0.f, 0.f, 0.f, 0.f);
        if (g < N_NODES) v = x4[(size_t)g * 32 + kc];
        xl4[r * 32 + (kc ^ (r & 3))] = v;
    }
    __syncthreads();

    const int tx = tid & 15;
    const int ty = tid >> 4;
    const int sw = ty & 3;

    float4 acc[4];
#pragma unroll
    for (int i = 0; i < 4; ++i) acc[i] = make_float4(0.f, 0.f, 0.f, 0.f);

    for (int kc = 0; kc < 32; ++kc) {
        float4 xv[4], wv[4];
#pragma unroll
        for (int i = 0; i < 4; ++i)
            xv[i] = xl4[(ty + 16 * i) * 32 + (kc ^ sw)];
#pragma unroll
        for (int j = 0; j < 4; ++j)
            wv[j] = wl4[(kc * 4 + j) * 16 + tx];
#pragma unroll
        for (int i = 0; i < 4; ++i) {
            acc[i].x = fmaf(xv[i].x, wv[0].x, acc[i].x);
            acc[i].y = fmaf(xv[i].x, wv[0].y, acc[i].y);
            acc[i].z = fmaf(xv[i].x, wv[0].z, acc[i].z);
            acc[i].w = fmaf(xv[i].x, wv[0].w, acc[i].w);
            acc[i].x = fmaf(xv[i].y, wv[1].x, acc[i].x);
            acc[i].y = fmaf(xv[i].y, wv[1].y, acc[i].y);
            acc[i].z = fmaf(xv[i].y, wv[1].z, acc[i].z);
            acc[i].w = fmaf(xv[i].y, wv[1].w, acc[i].w);
            acc[i].x = fmaf(xv[i].z, wv[2].x, acc[i].x);
            acc[i].y = fmaf(xv[i].z, wv[2].y, acc[i].y);
            acc[i].z = fmaf(xv[i].z, wv[2].z, acc[i].z);
            acc[i].w = fmaf(xv[i].z, wv[2].w, acc[i].w);
            acc[i].x = fmaf(xv[i].w, wv[3].x, acc[i].x);
            acc[i].y = fmaf(xv[i].w, wv[3].y, acc[i].y);
            acc[i].z = fmaf(xv[i].w, wv[3].z, acc[i].z);
            acc[i].w = fmaf(xv[i].w, wv[3].w, acc[i].w);
        }
    }

    ushort4* h4 = reinterpret_cast<ushort4*>(h16);
#pragma unroll
    for (int i = 0; i < 4; ++i) {
        const int r = row0 + ty + 16 * i;
        if (r < N_NODES) {
            ushort4 o;
            o.x = f2bf(acc[i].x);
            o.y = f2bf(acc[i].y);
            o.z = f2bf(acc[i].z);
            o.w = f2bf(acc[i].w);
            h4[(size_t)r * 16 + tx] = o;
        }
    }
}

// ---------------------------------------------------------------------------
// Pass 1: per-chunk (bucket,row&3) counts, written transposed:
// cntT[bc*NCH + blk] so the scan reads contiguously.
// ---------------------------------------------------------------------------
__global__ __launch_bounds__(512) void gc_count(const int* __restrict__ edst,
                                                int* __restrict__ cntT) {
    __shared__ int lh[NB4];
    const int t = threadIdx.x;
    for (int i = t; i < NB4; i += 512) lh[i] = 0;
    __syncthreads();
    const int base = blockIdx.x * CHUNK;
#pragma unroll
    for (int kk = 0; kk < CHUNK / 512; ++kk) {
        const int e = base + kk * 512 + t;
        if (e < N_EDGES) {
            const int d = edst[e];
            atomicAdd(&lh[((d >> 6) << 2) | (d & 3)], 1);
        }
    }
    __syncthreads();
    for (int i = t; i < NB4; i += 512) cntT[i * NCH + blockIdx.x] = lh[i];
}

// ---------------------------------------------------------------------------
// Parallel exclusive scan of cntT[SCAN_N] (contiguous), 3 passes, in-place.
// Afterwards: posT[f] = global start of piece f; f = bc*NCH + chunk.
// ---------------------------------------------------------------------------
__global__ __launch_bounds__(256) void gc_scan1(const int* __restrict__ a,
                                                int* __restrict__ bsum) {
    __shared__ int red[256];
    const int t = threadIdx.x;
    const int i0 = blockIdx.x * SCAN_BLK + t * 4;
    int v = 0;
#pragma unroll
    for (int j = 0; j < 4; ++j)
        if (i0 + j < SCAN_N) v += a[i0 + j];
    red[t] = v;
    __syncthreads();
#pragma unroll
    for (int s = 128; s > 0; s >>= 1) {
        if (t < s) red[t] += red[t + s];
        __syncthreads();
    }
    if (t == 0) bsum[blockIdx.x] = red[0];
}

__global__ __launch_bounds__(1024) void gc_scan2(int* __restrict__ bsum) {
    __shared__ int part[1024];
    const int t = threadIdx.x;
    const int v = (t < NSC) ? bsum[t] : 0;
    part[t] = v;
    __syncthreads();
#pragma unroll
    for (int off = 1; off < 1024; off <<= 1) {
        const int u = (t >= off) ? part[t - off] : 0;
        __syncthreads();
        part[t] += u;
        __syncthreads();
    }
    if (t < NSC) bsum[t] = part[t] - v;   // exclusive prefix of block sums
}

__global__ __launch_bounds__(256) void gc_scan3(int* __restrict__ a,
                                                const int* __restrict__ bsum) {
    __shared__ int part[256];
    const int t = threadIdx.x;
    const int i0 = blockIdx.x * SCAN_BLK + t * 4;
    int v[4];
    int s = 0;
#pragma unroll
    for (int j = 0; j < 4; ++j) {
        v[j] = (i0 + j < SCAN_N) ? a[i0 + j] : 0;
        s += v[j];
    }
    part[t] = s;
    __syncthreads();
#pragma unroll
    for (int off = 1; off < 256; off <<= 1) {
        const int u = (t >= off) ? part[t - off] : 0;
        __syncthreads();
        part[t] += u;
        __syncthreads();
    }
    int run = bsum[blockIdx.x] + part[t] - s;
#pragma unroll
    for (int j = 0; j < 4; ++j) {
        if (i0 + j < SCAN_N) a[i0 + j] = run;
        run += v[j];
    }
}

// ---------------------------------------------------------------------------
// Pass 3: bin edges grouped by (bucket, row&3). Piece sizes derived from
// posT (no histogram pass). Record: (row_in_bucket<<16)|src, weight bits.
// ---------------------------------------------------------------------------
__global__ __launch_bounds__(512) void gc_bin(const int* __restrict__ esrc,
                                              const int* __restrict__ edst,
                                              const float* __restrict__ ew,
                                              const int* __restrict__ posT,
                                              int2* __restrict__ tmp) {
    __shared__ int2 stage[CHUNK];     // 32 KB
    __shared__ int lh[NB4];           // 12.5 KB
    __shared__ int lcur[NB4];         // 12.5 KB
    __shared__ int gpos[NB4];         // 12.5 KB
    __shared__ int part[512];         // 2 KB   (total ~72 KB)

    const int t = threadIdx.x;
    const int blk = blockIdx.x;
    const int base = blk * CHUNK;

    // Piece size = posT[f+1] - posT[f] (flat successor == piece end).
    for (int i = t; i < NB4; i += 512) {
        const int f = i * NCH + blk;
        const int p = posT[f];
        const int pn = (f + 1 < SCAN_N) ? posT[f + 1] : N_EDGES;
        gpos[i] = p;
        lh[i] = pn - p;
    }
    __syncthreads();

    // Local exclusive scan of lh -> lcur (stage cursors). 7 entries/thread.
    {
        const int b0 = t * 7;
        int s = 0;
#pragma unroll
        for (int j = 0; j < 7; ++j)
            if (b0 + j < NB4) s += lh[b0 + j];
        part[t] = s;
        __syncthreads();
#pragma unroll
        for (int off = 1; off < 512; off <<= 1) {
            const int u = (t >= off) ? part[t - off] : 0;
            __syncthreads();
            part[t] += u;
            __syncthreads();
        }
        int run = part[t] - s;
#pragma unroll
        for (int j = 0; j < 7; ++j) {
            if (b0 + j < NB4) {
                lcur[b0 + j] = run;
                run += lh[b0 + j];
            }
        }
    }
    __syncthreads();

    // Stage edges grouped by (bucket, row&3) (LDS cursor atomics only).
#pragma unroll
    for (int kk = 0; kk < CHUNK / 512; ++kk) {
        const int e = base + kk * 512 + t;
        if (e < N_EDGES) {
            const int d = edst[e];
            const int bc = ((d >> 6) << 2) | (d & 3);
            const int p = atomicAdd(&lcur[bc], 1);
            stage[p] = make_int2((int)(((unsigned)(d & 63) << 16) | (unsigned)esrc[e]),
                                 __float_as_int(ew[e]));
        }
    }
    __syncthreads();

    // Flush pieces to precomputed global slots (no global atomics).
    const int wv = t >> 6, ln = t & 63;
    for (int bc = wv; bc < NB4; bc += 8) {
        const int cnt = lh[bc];
        if (!cnt) continue;
        const int gbase = gpos[bc];
        const int lb = lcur[bc] - cnt;   // lcur advanced by exactly cnt
        for (int i = ln; i < cnt; i += 64) tmp[gbase + i] = stage[lb + i];
    }
}

// ---------------------------------------------------------------------------
// Pass 4: fused aggregate + ReLU. One block (4 waves) per bucket; private
// per-wave 64x64 tile. 4 row-class streams (row%4 = 0..3) in lockstep:
// the 4 RMWs per group hit provably-distinct LDS addresses, so the reads
// issue back-to-back (pipelined) instead of serializing at ~130cy each.
// ---------------------------------------------------------------------------
__global__ __launch_bounds__(256) void gc_bagg(const unsigned short* __restrict__ h16,
                                               const int* __restrict__ posT,
                                               const int2* __restrict__ tmp,
                                               float* __restrict__ out) {
    __shared__ float tiles[4 * 64 * 64];   // 64 KB: one private tile per wave
    const int t = threadIdx.x;
    const int b = blockIdx.x;
    const int wv = t >> 6;
    const int ln = t & 63;

    for (int i = t; i < 4 * 4096; i += 256) tiles[i] = 0.f;
    __syncthreads();

    float* tile = &tiles[wv * 4096];

    // Class segment bounds + this wave's quarter of each class.
    const int f0 = (b * 4) * NCH;
    const int s0 = posT[f0];
    const int s1 = posT[f0 + NCH];
    const int s2 = posT[f0 + 2 * NCH];
    const int s3 = posT[f0 + 3 * NCH];
    const int s4 = (b * 4 + 4 < NB4) ? posT[f0 + 4 * NCH] : N_EDGES;
    const int c0 = s1 - s0, c1 = s2 - s1, c2 = s3 - s2, c3 = s4 - s3;
    const int jb0 = s0 + ((c0 * wv) >> 2), je0 = s0 + ((c0 * (wv + 1)) >> 2);
    const int jb1 = s1 + ((c1 * wv) >> 2), je1 = s1 + ((c1 * (wv + 1)) >> 2);
    const int jb2 = s2 + ((c2 * wv) >> 2), je2 = s2 + ((c2 * (wv + 1)) >> 2);
    const int jb3 = s3 + ((c3 * wv) >> 2), je3 = s3 + ((c3 * (wv + 1)) >> 2);

    const int n0 = je0 - jb0, n1 = je1 - jb1, n2 = je2 - jb2, n3 = je3 - jb3;
    const int n = min(min(n0, n1), min(n2, n3));

    int k = 0;
    for (; k + 2 <= n; k += 2) {
        const int2 r0 = tmp[jb0 + k];
        const int2 r1 = tmp[jb1 + k];
        const int2 r2 = tmp[jb2 + k];
        const int2 r3 = tmp[jb3 + k];
        const int2 r4 = tmp[jb0 + k + 1];
        const int2 r5 = tmp[jb1 + k + 1];
        const int2 r6 = tmp[jb2 + k + 1];
        const int2 r7 = tmp[jb3 + k + 1];
        const float h0 = bf2f(h16[(size_t)(r0.x & 0xFFFF) * OUT_DIM + ln]);
        const float h1 = bf2f(h16[(size_t)(r1.x & 0xFFFF) * OUT_DIM + ln]);
        const float h2 = bf2f(h16[(size_t)(r2.x & 0xFFFF) * OUT_DIM + ln]);
        const float h3 = bf2f(h16[(size_t)(r3.x & 0xFFFF) * OUT_DIM + ln]);
        const float h4 = bf2f(h16[(size_t)(r4.x & 0xFFFF) * OUT_DIM + ln]);
        const float h5 = bf2f(h16[(size_t)(r5.x & 0xFFFF) * OUT_DIM + ln]);
        const float h6 = bf2f(h16[(size_t)(r6.x & 0xFFFF) * OUT_DIM + ln]);
        const float h7 = bf2f(h16[(size_t)(r7.x & 0xFFFF) * OUT_DIM + ln]);
        {   // group A: depth 0, classes 0-3 -> distinct rows mod 4
            float* p0 = &tile[((r0.x >> 16) & 63) * 64 + ln];
            float* p1 = &tile[((r1.x >> 16) & 63) * 64 + ln];
            float* p2 = &tile[((r2.x >> 16) & 63) * 64 + ln];
            float* p3 = &tile[((r3.x >> 16) & 63) * 64 + ln];
            const float a0 = *p0;
            const float a1 = *p1;
            const float a2 = *p2;
            const float a3 = *p3;
            *p0 = fmaf(__int_as_float(r0.y), h0, a0);
            *p1 = fmaf(__int_as_float(r1.y), h1, a1);
            *p2 = fmaf(__int_as_float(r2.y), h2, a2);
            *p3 = fmaf(__int_as_float(r3.y), h3, a3);
        }
        {   // group B: depth 1 (ordered after group A per class)
            float* p0 = &tile[((r4.x >> 16) & 63) * 64 + ln];
            float* p1 = &tile[((r5.x >> 16) & 63) * 64 + ln];
            float* p2 = &tile[((r6.x >> 16) & 63) * 64 + ln];
            float* p3 = &tile[((r7.x >> 16) & 63) * 64 + ln];
            const float a0 = *p0;
            const float a1 = *p1;
            const float a2 = *p2;
            const float a3 = *p3;
            *p0 = fmaf(__int_as_float(r4.y), h4, a0);
            *p1 = fmaf(__int_as_float(r5.y), h5, a1);
            *p2 = fmaf(__int_as_float(r6.y), h6, a2);
            *p3 = fmaf(__int_as_float(r7.y), h7, a3);
        }
    }
    // Tails (small: class imbalance + odd remainder), serial RMW.
#define GC_TAIL(JB, JE)                                                        \
    for (int j = (JB) + k; j < (JE); ++j) {                                    \
        const int2 r = tmp[j];                                                 \
        const int src = r.x & 0xFFFF;                                          \
        const int row = (r.x >> 16) & 63;                                      \
        tile[row * 64 + ln] += __int_as_float(r.y) *                           \
                               bf2f(h16[(size_t)src * OUT_DIM + ln]);          \
    }
    GC_TAIL(jb0, je0)
    GC_TAIL(jb1, je1)
    GC_TAIL(jb2, je2)
    GC_TAIL(jb3, je3)
#undef GC_TAIL
    __syncthreads();

    // Merge 4 private tiles + ReLU + coalesced float4 store.
    const int node0 = b * 64;
    float4* o4 = reinterpret_cast<float4*>(out);
    const float4* t4 = reinterpret_cast<const float4*>(tiles);
    for (int i = t; i < 1024; i += 256) {
        const float4 a = t4[i];
        const float4 b2 = t4[1024 + i];
        const float4 c = t4[2048 + i];
        const float4 d = t4[3072 + i];
        float4 s;
        s.x = fmaxf(a.x + b2.x + c.x + d.x, 0.f);
        s.y = fmaxf(a.y + b2.y + c.y + d.y, 0.f);
        s.z = fmaxf(a.z + b2.z + c.z + d.z, 0.f);
        s.w = fmaxf(a.w + b2.w + c.w + d.w, 0.f);
        const int r = i >> 4;
        const int gn = node0 + r;
        if (gn < N_NODES) o4[(size_t)gn * 16 + (i & 15)] = s;
    }
}

extern "C" void kernel_launch(void* const* d_in, const int* in_sizes, int n_in,
                              void* d_out, int out_size, void* d_ws, size_t ws_size,
                              hipStream_t stream) {
    const float* x    = (const float*)d_in[0];
    const int*   esrc = (const int*)d_in[1];
    const int*   edst = (const int*)d_in[2];
    const float* ew   = (const float*)d_in[3];
    const float* w    = (const float*)d_in[4];
    float* out = (float*)d_out;

    // Workspace layout (~15.3 MB):
    unsigned short* h16 = (unsigned short*)d_ws;                 // 3.2M bf16 (6.4 MB)
    int*  cntT = (int*)(h16 + (size_t)N_NODES * OUT_DIM);        // 613,088 ints (-> posT)
    int*  bsum = cntT + 613120;                                  // 599 ints
    int2* tmp  = (int2*)(bsum + 1024);                           // 800,000 int2 (6.4 MB)

    // h = x @ w (bf16 store)
    gc_gemm<<<(N_NODES + ROWS - 1) / ROWS, 256, 0, stream>>>(x, w, h16);

    // Deterministic (bucket, row&3) binning — no global atomics, no memsets.
    gc_count<<<NCH, 512, 0, stream>>>(edst, cntT);
    gc_scan1<<<NSC, 256, 0, stream>>>(cntT, bsum);
    gc_scan2<<<1, 1024, 0, stream>>>(bsum);
    gc_scan3<<<NSC, 256, 0, stream>>>(cntT, bsum);   // cntT -> posT in place
    gc_bin<<<NCH, 512, 0, stream>>>(esrc, edst, ew, cntT, tmp);

    // Per-bucket fused gather-accumulate + ReLU (4-stream pipelined RMW).
    gc_bagg<<<NB, 256, 0, stream>>>(h16, cntT, tmp, out);
}